// Round 1
// baseline (2366.171 us; speedup 1.0000x reference)
//
#include <hip/hip_runtime.h>
#include <cstdint>
#include <cstddef>

// Problem dims (fixed by reference)
#define B_    64
#define T_    4096
#define H_    128
#define C1_   64
#define NCLS_ 40
#define NG_   512    // 4*H_

#define LOG2E_    1.4426950408889634f
#define TWOLOG2E_ 2.8853900817779268f

typedef _Float16 half2_t __attribute__((ext_vector_type(2)));
typedef _Float16 half8_t __attribute__((ext_vector_type(8)));
typedef float    f32x4_t __attribute__((ext_vector_type(4)));

__device__ __forceinline__ float fdot2(half2_t a, half2_t b, float c){
#if defined(__has_builtin) && __has_builtin(__builtin_amdgcn_fdot2)
  return __builtin_amdgcn_fdot2(a, b, c, false);   // v_dot2_f32_f16, full-rate
#else
  return fmaf((float)a.x, (float)b.x, fmaf((float)a.y, (float)b.y, c));
#endif
}
__device__ __forceinline__ half2_t bc2(unsigned int u){ return __builtin_bit_cast(half2_t, u); }
__device__ __forceinline__ half2_t pack2(float a, float b){
  half2_t r; r.x = (_Float16)a; r.y = (_Float16)b; return r;   // RTNE
}
template<int CTRL>
__device__ __forceinline__ float qperm(float x){
  return __int_as_float(__builtin_amdgcn_update_dpp(0, __float_as_int(x), CTRL, 0xF, 0xF, true));
}

// ---------------- kernel 1: 3x3 second-moment stats of x over B*T ----------------
__global__ __launch_bounds__(256) void stats_kernel(const float* __restrict__ x,
                                                    float* __restrict__ stats){
  int t = blockIdx.x * 256 + threadIdx.x;
  const float4* xv = (const float4*)x + (size_t)t * 3;
  float4 a = xv[0], b = xv[1], c = xv[2];
  float x0[4] = {a.x, a.w, b.z, c.y};
  float x1[4] = {a.y, b.x, b.w, c.z};
  float x2[4] = {a.z, b.y, c.x, c.w};
  float s[9] = {0,0,0,0,0,0,0,0,0};
  #pragma unroll
  for (int r=0;r<4;++r){
    s[0]+=x0[r]; s[1]+=x1[r]; s[2]+=x2[r];
    s[3]+=x0[r]*x0[r]; s[4]+=x0[r]*x1[r]; s[5]+=x0[r]*x2[r];
    s[6]+=x1[r]*x1[r]; s[7]+=x1[r]*x2[r]; s[8]+=x2[r]*x2[r];
  }
  __shared__ float red[9][256];
  #pragma unroll
  for (int j=0;j<9;++j) red[j][threadIdx.x] = s[j];
  __syncthreads();
  if (threadIdx.x < 9){
    float sum = 0.f;
    for (int i=0;i<256;++i) sum += red[threadIdx.x][i];
    atomicAdd(&stats[threadIdx.x], sum);
  }
}

// Fold conv + BN(train stats) + gamma/beta into per-channel affine. conv_b cancels.
__device__ __forceinline__ void chan_affine(int c, const float* __restrict__ conv_w,
    const float* __restrict__ bn_g, const float* __restrict__ bn_b,
    const float* __restrict__ stats,
    float& A0, float& A1, float& A2, float& Bc){
  const float Ninv = 1.0f / (float)(B_*T_);
  float m0=stats[0]*Ninv, m1=stats[1]*Ninv, m2=stats[2]*Ninv;
  float c00=stats[3]*Ninv-m0*m0, c01=stats[4]*Ninv-m0*m1, c02=stats[5]*Ninv-m0*m2;
  float c11=stats[6]*Ninv-m1*m1, c12=stats[7]*Ninv-m1*m2, c22=stats[8]*Ninv-m2*m2;
  float w0=conv_w[c*3+0], w1=conv_w[c*3+1], w2=conv_w[c*3+2];
  float var = w0*(w0*c00 + 2.f*(w1*c01 + w2*c02)) + w1*(w1*c11 + 2.f*w2*c12) + w2*w2*c22;
  float sc = bn_g[c] * rsqrtf(var + 1e-5f);
  A0 = w0*sc; A1 = w1*sc; A2 = w2*sc;
  Bc = bn_b[c] - (w0*m0 + w1*m1 + w2*m2)*sc;
}

// ---------------- kernel 2 (Tier A fallback): y = relu(affine(x)) as f16 [B][T+2][64] ----------------
__global__ __launch_bounds__(256) void y_kernel(const float* __restrict__ x,
    const float* __restrict__ conv_w, const float* __restrict__ bn_g,
    const float* __restrict__ bn_b, const float* __restrict__ stats,
    _Float16* __restrict__ yg){
  __shared__ float4 coef[C1_];
  int tid = threadIdx.x;
  if (tid < C1_){
    float A0,A1,A2,Bc; chan_affine(tid, conv_w, bn_g, bn_b, stats, A0,A1,A2,Bc);
    coef[tid] = make_float4(A0,A1,A2,Bc);
  }
  __syncthreads();
  size_t idx = (size_t)blockIdx.x * 256 + tid;      // b*T + t
  int b = (int)(idx >> 12), t = (int)(idx & (T_-1));
  const float* xp = x + idx*3;
  float x0 = xp[0], x1 = xp[1], x2 = xp[2];
  unsigned int ob[32];
  #pragma unroll
  for (int c=0; c<C1_; c+=2){
    float4 c0 = coef[c], c1 = coef[c+1];
    float v0 = fmaxf(fmaf(c0.x,x0, fmaf(c0.y,x1, fmaf(c0.z,x2, c0.w))), 0.f);
    float v1 = fmaxf(fmaf(c1.x,x0, fmaf(c1.y,x1, fmaf(c1.z,x2, c1.w))), 0.f);
    ob[c>>1] = __builtin_bit_cast(unsigned int, pack2(v0, v1));
  }
  uint4* dst = (uint4*)(yg + ((size_t)b*(T_+2) + t)*C1_);
  #pragma unroll
  for (int i=0;i<8;++i) dst[i] = ((uint4*)ob)[i];
}

// ---------------- kernel 2' (primary): P = sg*(W_ih @ relu(affine(x)) + b_ih + b_hh) ----------------
// MFMA f16 GEMM, M = B*T (64 rows/block), K = 64, N = 512. Output [b][T+2][512], rows T,T+1 junk pads.
// Gate exp2-scales (sg) and both biases folded in -> LSTM step needs only "accv + P".
template<typename PT>
__global__ __launch_bounds__(256) void gemm_p_kernel(
    const float* __restrict__ x, const float* __restrict__ conv_w,
    const float* __restrict__ bn_g, const float* __restrict__ bn_b,
    const float* __restrict__ stats, const float* __restrict__ w_ih,
    const float* __restrict__ b_ih, const float* __restrict__ b_hh,
    PT* __restrict__ P){
  __shared__ float4 coef[C1_];
  __shared__ __align__(16) _Float16 ylds[64][80];   // pad 64->80: 16B-aligned rows, ~4-way banks
  int tid = threadIdx.x;
  if (tid < C1_){
    float A0,A1,A2,Bc; chan_affine(tid, conv_w, bn_g, bn_b, stats, A0,A1,A2,Bc);
    coef[tid] = make_float4(A0,A1,A2,Bc);
  }
  __syncthreads();
  int Mbase = blockIdx.x * 64;
  int bb = Mbase >> 12, t0 = Mbase & (T_-1);        // 64 | T_, never straddles a batch
  // stage y tile [64 rows][64 ch] f16
  {
    int r = tid >> 2, cg = tid & 3;
    const float* xp = x + (size_t)(Mbase + r)*3;
    float x0 = xp[0], x1 = xp[1], x2 = xp[2];
    #pragma unroll
    for (int i=0;i<8;++i){
      int c = cg*16 + 2*i;
      float4 c0 = coef[c], c1 = coef[c+1];
      float v0 = fmaxf(fmaf(c0.x,x0, fmaf(c0.y,x1, fmaf(c0.z,x2, c0.w))), 0.f);
      float v1 = fmaxf(fmaf(c1.x,x0, fmaf(c1.y,x1, fmaf(c1.z,x2, c1.w))), 0.f);
      ylds[r][c]   = (_Float16)v0;
      ylds[r][c+1] = (_Float16)v1;
    }
  }
  // B fragments: wave wv owns n in [wv*128, wv*128+128). B[k][n]: lane -> n=lane&15, regs -> k.
  int lane = tid & 63, wv = tid >> 6;
  int rfrag = lane & 15, kgrp = lane >> 4;
  int kb8 = kgrp * 8;
  half8_t bf[8][2];
  float sgb[8];
  #pragma unroll
  for (int nt=0; nt<8; ++nt){
    int n = wv*128 + nt*16 + rfrag;
    float sg = ((n >> 7) == 2) ? TWOLOG2E_ : -LOG2E_;
    sgb[nt] = sg * (b_ih[n] + b_hh[n]);
    #pragma unroll
    for (int kb=0; kb<2; ++kb){
      const float4* wp = (const float4*)(w_ih + (size_t)n*C1_ + kb*32 + kb8);
      float4 u0 = wp[0], u1 = wp[1];
      half8_t hv;
      hv[0]=(_Float16)(sg*u0.x); hv[1]=(_Float16)(sg*u0.y);
      hv[2]=(_Float16)(sg*u0.z); hv[3]=(_Float16)(sg*u0.w);
      hv[4]=(_Float16)(sg*u1.x); hv[5]=(_Float16)(sg*u1.y);
      hv[6]=(_Float16)(sg*u1.z); hv[7]=(_Float16)(sg*u1.w);
      bf[nt][kb] = hv;
    }
  }
  __syncthreads();
  size_t pbase = ((size_t)bb*(T_+2) + t0) * NG_;
  #pragma unroll
  for (int mt=0; mt<4; ++mt){
    // A frag: row = lane&15, k = (lane>>4)*8 + j  (verified 16x16x32 layout)
    half8_t a0 = *(const half8_t*)&ylds[mt*16 + rfrag][kb8];
    half8_t a1 = *(const half8_t*)&ylds[mt*16 + rfrag][32 + kb8];
    #pragma unroll
    for (int nt=0; nt<8; ++nt){
      f32x4_t d = {0.f,0.f,0.f,0.f};
      d = __builtin_amdgcn_mfma_f32_16x16x32_f16(a0, bf[nt][0], d, 0, 0, 0);
      d = __builtin_amdgcn_mfma_f32_16x16x32_f16(a1, bf[nt][1], d, 0, 0, 0);
      int ncol = wv*128 + nt*16 + rfrag;            // D col = lane&15
      #pragma unroll
      for (int v=0; v<4; ++v){
        int rr = mt*16 + kgrp*4 + v;                // D row = (lane>>4)*4 + reg
        P[pbase + (size_t)rr*NG_ + ncol] = (PT)(d[v] + sgb[nt]);
      }
    }
  }
}

// ---------------- kernel 3: persistent per-batch LSTM ----------------
// MODE 0: precomputed P f32   MODE 1: precomputed P f16
// MODE 2: yg prefetch (old Tier A)   MODE 3: in-kernel y (old Tier B)
// 64 blocks x 512 threads (8 waves, 2/SIMD). thread t: k=t>>2, w=t&3.
// MODE<=1: pre-barrier phase is ONE dword load + pointer bump; W_ih work hoisted to gemm_p.
template<int MODE>
__global__ __launch_bounds__(512,2) void lstm_kernel(
    const void* __restrict__ Pv,
    const _Float16* __restrict__ yg, const float* __restrict__ x,
    const float* __restrict__ conv_w, const float* __restrict__ bn_g,
    const float* __restrict__ bn_b, const float* __restrict__ stats,
    const float* __restrict__ w_ih, const float* __restrict__ b_ih,
    const float* __restrict__ b_hh, const float* __restrict__ w_hh,
    const float* __restrict__ h0, const float* __restrict__ c0,
    const float* __restrict__ out_w, const float* __restrict__ out_b,
    float* __restrict__ out){
  int b = blockIdx.x, t = threadIdx.x;
  int k = t >> 2, w = t & 3;
  __shared__ __align__(16) _Float16 hbuf[2][H_];
  __shared__ __align__(16) _Float16 ybuf[4][C1_];   // Tier B only

  // weights prescaled by gate exp2-scale: sg = -log2e (I,F,O), +2log2e (G)
  half2_t wh[4][16];
  half2_t wy[4][8];                                 // MODE>=2 only (else DCE'd)
  #pragma unroll
  for (int g=0; g<4; ++g){
    float sg = (g==2) ? TWOLOG2E_ : -LOG2E_;
    const float4* p = (const float4*)(w_hh + (size_t)(g*H_ + k)*H_ + w*32);
    #pragma unroll
    for (int i=0;i<8;++i){
      float4 v = p[i];
      wh[g][2*i]   = pack2(sg*v.x, sg*v.y);
      wh[g][2*i+1] = pack2(sg*v.z, sg*v.w);
    }
    if constexpr (MODE >= 2){
      const float4* py = (const float4*)(w_ih + (size_t)(g*H_ + k)*C1_ + w*16);
      #pragma unroll
      for (int i=0;i<4;++i){
        float4 v = py[i];
        wy[g][2*i]   = pack2(sg*v.x, sg*v.y);
        wy[g][2*i+1] = pack2(sg*v.z, sg*v.w);
      }
    }
  }
  float biasSel = 0.f;
  if constexpr (MODE >= 2){
    float sg = (w==2) ? TWOLOG2E_ : -LOG2E_;
    biasSel = sg * (b_ih[w*H_+k] + b_hh[w*H_+k]);
  }
  float Aa = (w==2) ?  1.f : 0.f;
  float Bb = (w==0) ? TWOLOG2E_ : ((w==2) ? -2.f : 1.f);
  bool o1 = (w & 1) != 0;
  bool o2 = (w & 2) != 0;

  float cs = TWOLOG2E_ * c0[(size_t)b*H_ + k];      // scaled cell state (lanes 0,1 authoritative)
  if (w == 0) hbuf[0][k] = (_Float16)h0[(size_t)b*H_ + k];

  // ---- Tier B (in-kernel y) setup ----
  int yc = t >> 3; bool prod = ((t & 7) == 0);
  float ya0=0, ya1=0, ya2=0, ya3=0;
  float xs0=0, xs1=0, xs2=0, xn0=0, xn1=0, xn2=0;
  const float* xb = x + (size_t)b*T_*3;
  if constexpr (MODE == 3){
    chan_affine(yc, conv_w, bn_g, bn_b, stats, ya0, ya1, ya2, ya3);
    if (prod){
      float v0 = fmaf(ya0, xb[0], fmaf(ya1, xb[1], fmaf(ya2, xb[2], ya3)));
      float v1 = fmaf(ya0, xb[3], fmaf(ya1, xb[4], fmaf(ya2, xb[5], ya3)));
      ybuf[0][yc] = (_Float16)fmaxf(v0, 0.f);
      ybuf[1][yc] = (_Float16)fmaxf(v1, 0.f);
    }
    xs0 = xb[6];  xs1 = xb[7];  xs2 = xb[8];
    xn0 = xb[9];  xn1 = xb[10]; xn2 = xb[11];
  }
  // ---- Tier A yg preload: depth-2 prefetch, ring-4 register buffers ----
  const _Float16* ypref = nullptr;
  uint4 ypf[4][2];
  if constexpr (MODE == 2){
    const _Float16* ygb = yg + (size_t)b*(T_+2)*C1_ + w*16;
    ypf[0][0] = *(const uint4*)(ygb);           ypf[0][1] = *(const uint4*)(ygb + 8);
    ypf[1][0] = *(const uint4*)(ygb + C1_);     ypf[1][1] = *(const uint4*)(ygb + C1_ + 8);
    ypref = ygb + 2*C1_;
  }
  // ---- P preload (MODE 0/1): depth-2 prefetch, ring-4 scalar regs ----
  const float*    ppf = nullptr;
  const _Float16* pph = nullptr;
  float    pff[4];
  _Float16 pfh[4];
  if constexpr (MODE == 0){
    ppf = (const float*)Pv + (size_t)b*(T_+2)*NG_ + (unsigned)(w*H_ + k);
    pff[0] = ppf[0]; pff[1] = ppf[NG_];
    ppf += 2*NG_;                                   // -> P(step+2) at step=0; rows T,T+1 pads
  }
  if constexpr (MODE == 1){
    pph = (const _Float16*)Pv + (size_t)b*(T_+2)*NG_ + (unsigned)(w*H_ + k);
    pfh[0] = pph[0]; pfh[1] = pph[NG_];
    pph += 2*NG_;
  }
  __syncthreads();

  #pragma unroll 4
  for (int step=0; step<T_; ++step){
    int p  = step & 1;                              // const-folded per unrolled copy
    int r4 = step & 3;
    float acc[4] = {0.f,0.f,0.f,0.f};
    float pv = 0.f;
    // ===== pre-barrier =====
    if constexpr (MODE == 0){
      pv = pff[r4];
      pff[(r4+2)&3] = *ppf; ppf += NG_;             // vmcnt; used 2 iters later
    } else if constexpr (MODE == 1){
      pv = (float)pfh[r4];
      pfh[(r4+2)&3] = *pph; pph += NG_;
    } else if constexpr (MODE == 2){
      ypf[(r4+2)&3][0] = *(const uint4*)(ypref);
      ypf[(r4+2)&3][1] = *(const uint4*)(ypref + 8);
      ypref += C1_;
      uint4 yv0 = ypf[r4][0], yv1 = ypf[r4][1];
      half2_t y0_ = bc2(yv0.x), y1_ = bc2(yv0.y), y2_ = bc2(yv0.z), y3_ = bc2(yv0.w);
      half2_t y4_ = bc2(yv1.x), y5_ = bc2(yv1.y), y6_ = bc2(yv1.z), y7_ = bc2(yv1.w);
      #pragma unroll
      for (int g=0; g<4; ++g){
        acc[g] = fdot2(wy[g][0], y0_, acc[g]);
        acc[g] = fdot2(wy[g][1], y1_, acc[g]);
        acc[g] = fdot2(wy[g][2], y2_, acc[g]);
        acc[g] = fdot2(wy[g][3], y3_, acc[g]);
        acc[g] = fdot2(wy[g][4], y4_, acc[g]);
        acc[g] = fdot2(wy[g][5], y5_, acc[g]);
        acc[g] = fdot2(wy[g][6], y6_, acc[g]);
        acc[g] = fdot2(wy[g][7], y7_, acc[g]);
      }
    } else {
      const _Float16* yb2 = &ybuf[r4][w*16];
      uint4 yv0 = *(const uint4*)(yb2);
      uint4 yv1 = *(const uint4*)(yb2 + 8);
      half2_t y0_ = bc2(yv0.x), y1_ = bc2(yv0.y), y2_ = bc2(yv0.z), y3_ = bc2(yv0.w);
      half2_t y4_ = bc2(yv1.x), y5_ = bc2(yv1.y), y6_ = bc2(yv1.z), y7_ = bc2(yv1.w);
      #pragma unroll
      for (int g=0; g<4; ++g){
        acc[g] = fdot2(wy[g][0], y0_, acc[g]);
        acc[g] = fdot2(wy[g][1], y1_, acc[g]);
        acc[g] = fdot2(wy[g][2], y2_, acc[g]);
        acc[g] = fdot2(wy[g][3], y3_, acc[g]);
        acc[g] = fdot2(wy[g][4], y4_, acc[g]);
        acc[g] = fdot2(wy[g][5], y5_, acc[g]);
        acc[g] = fdot2(wy[g][6], y6_, acc[g]);
        acc[g] = fdot2(wy[g][7], y7_, acc[g]);
      }
      float yn = fmaf(ya0, xs0, fmaf(ya1, xs1, fmaf(ya2, xs2, ya3)));
      if (prod) ybuf[(step+2) & 3][yc] = (_Float16)fmaxf(yn, 0.f);
      xs0=xn0; xs1=xn1; xs2=xn2;
      { int t4 = (step+4 < T_) ? step+4 : T_-1;
        const float* xp = xb + 3*t4; xn0=xp[0]; xn1=xp[1]; xn2=xp[2]; }
    }
    // ===== barrier (LDS-only drain; vmcnt loads stay in flight) =====
    asm volatile("s_waitcnt lgkmcnt(0)" ::: "memory");
    __builtin_amdgcn_s_barrier();
    asm volatile("" ::: "memory");
    // ===== post-barrier: h-dots over [w*32, w*32+32) =====
    const _Float16* hb = &hbuf[p][w*32];
    #pragma unroll
    for (int i=0;i<4;++i){
      uint4 hv = *(const uint4*)(hb + 8*i);
      half2_t h0_ = bc2(hv.x), h1_ = bc2(hv.y), h2_ = bc2(hv.z), h3_ = bc2(hv.w);
      #pragma unroll
      for (int g=0; g<4; ++g){
        acc[g] = fdot2(wh[g][4*i+0], h0_, acc[g]);
        acc[g] = fdot2(wh[g][4*i+1], h1_, acc[g]);
        acc[g] = fdot2(wh[g][4*i+2], h2_, acc[g]);
        acc[g] = fdot2(wh[g][4*i+3], h3_, acc[g]);
      }
    }
    // reduce-scatter over quad: lane w ends with gate w's total
    float b01, b23;
    { float s0 = o1 ? acc[0] : acc[1];  float k0 = o1 ? acc[1] : acc[0];
      float s1 = o1 ? acc[2] : acc[3];  float k1 = o1 ? acc[3] : acc[2];
      b01 = k0 + qperm<0xB1>(s0);
      b23 = k1 + qperm<0xB1>(s1); }
    float accv;
    { float s = o2 ? b01 : b23;  float kk = o2 ? b23 : b01;
      accv = kk + qperm<0x4E>(s); }
    // activation (prescaled): act = Aa + Bb*rcp(1+exp2(v))
    float v;
    if constexpr (MODE <= 1) v = accv + pv;         // bias folded into P
    else                     v = accv + biasSel;
    float e = __builtin_amdgcn_exp2f(v);
    float act = fmaf(Bb, __builtin_amdgcn_rcpf(1.f + e), Aa);
    float dA = qperm<0x1B>(act);                    // lane0 <- O
    float bp = qperm<0x4E>(act);                    // lane0 <- G
    float pp = act * (o1 ? cs : bp);                // lane0: I_s*G ; lane1: F*cs
    float cps = pp + qperm<0xB1>(pp);               // lanes 0,1: scaled c'
    cs = cps;
    float th = fmaf(-2.f, __builtin_amdgcn_rcpf(1.f + __builtin_amdgcn_exp2f(cps)), 1.f);
    float h = th * dA;
    if (w == 0) hbuf[1-p][k] = (_Float16)h;
  }
  __syncthreads();
  // classifier epilogue on final h (T even -> buffer 0)
  if (t < NCLS_){
    float s = out_b[t];
    #pragma unroll 8
    for (int kk=0; kk<H_; ++kk)
      s = fmaf(out_w[t*H_ + kk], (float)hbuf[0][kk], s);
    out[(size_t)b*NCLS_ + t] = s;
  }
}

extern "C" void kernel_launch(void* const* d_in, const int* in_sizes, int n_in,
                              void* d_out, int out_size, void* d_ws, size_t ws_size,
                              hipStream_t stream){
  const float* x      = (const float*)d_in[0];
  const float* conv_w = (const float*)d_in[1];
  // d_in[2] = conv_b: cancels exactly inside BN(train stats) — unused
  const float* bn_g   = (const float*)d_in[3];
  const float* bn_b   = (const float*)d_in[4];
  const float* w_ih   = (const float*)d_in[5];
  const float* b_ih   = (const float*)d_in[6];
  const float* w_hh   = (const float*)d_in[7];
  const float* b_hh   = (const float*)d_in[8];
  const float* out_w  = (const float*)d_in[9];
  const float* out_b  = (const float*)d_in[10];
  const float* h0     = (const float*)d_in[11];
  const float* c0     = (const float*)d_in[12];
  float* out      = (float*)d_out;
  float* stats    = (float*)d_ws;
  char*  wsb      = (char*)d_ws;
  const size_t needP32 = 4096 + (size_t)B_*(T_+2)*NG_*sizeof(float);      // ~537 MB
  const size_t needP16 = 4096 + (size_t)B_*(T_+2)*NG_*sizeof(_Float16);   // ~269 MB
  const size_t needA   = 4096 + (size_t)B_*(T_+2)*C1_*sizeof(_Float16);   // ~33.6 MB

  hipMemsetAsync(d_ws, 0, 64, stream);
  stats_kernel<<<256, 256, 0, stream>>>(x, stats);
  if (ws_size >= needP32){
    float* P = (float*)(wsb + 4096);
    gemm_p_kernel<float><<<(B_*T_)/64, 256, 0, stream>>>(x, conv_w, bn_g, bn_b, stats,
                                                         w_ih, b_ih, b_hh, P);
    lstm_kernel<0><<<B_, 512, 0, stream>>>(P, nullptr, x, conv_w, bn_g, bn_b, stats,
                                           w_ih, b_ih, b_hh, w_hh, h0, c0, out_w, out_b, out);
  } else if (ws_size >= needP16){
    _Float16* P = (_Float16*)(wsb + 4096);
    gemm_p_kernel<_Float16><<<(B_*T_)/64, 256, 0, stream>>>(x, conv_w, bn_g, bn_b, stats,
                                                            w_ih, b_ih, b_hh, P);
    lstm_kernel<1><<<B_, 512, 0, stream>>>(P, nullptr, x, conv_w, bn_g, bn_b, stats,
                                           w_ih, b_ih, b_hh, w_hh, h0, c0, out_w, out_b, out);
  } else if (ws_size >= needA){
    _Float16* yg = (_Float16*)(wsb + 4096);
    y_kernel<<<(B_*T_)/256, 256, 0, stream>>>(x, conv_w, bn_g, bn_b, stats, yg);
    lstm_kernel<2><<<B_, 512, 0, stream>>>(nullptr, yg, x, conv_w, bn_g, bn_b, stats,
                                           w_ih, b_ih, b_hh, w_hh, h0, c0, out_w, out_b, out);
  } else {
    lstm_kernel<3><<<B_, 512, 0, stream>>>(nullptr, nullptr, x, conv_w, bn_g, bn_b, stats,
                                           w_ih, b_ih, b_hh, w_hh, h0, c0, out_w, out_b, out);
  }
}

// Round 2
// 2173.278 us; speedup vs baseline: 1.0888x; 1.0888x over previous
//
#include <hip/hip_runtime.h>
#include <cstdint>
#include <cstddef>

// Problem dims (fixed by reference)
#define B_    64
#define T_    4096
#define H_    128
#define C1_   64
#define NCLS_ 40

#define LOG2E_    1.4426950408889634f
#define TWOLOG2E_ 2.8853900817779268f

typedef _Float16 half2_t __attribute__((ext_vector_type(2)));
typedef _Float16 half8_t __attribute__((ext_vector_type(8)));
typedef float    f32x4_t __attribute__((ext_vector_type(4)));

__device__ __forceinline__ float fdot2(half2_t a, half2_t b, float c){
#if defined(__has_builtin) && __has_builtin(__builtin_amdgcn_fdot2)
  return __builtin_amdgcn_fdot2(a, b, c, false);   // v_dot2_f32_f16, full-rate
#else
  return fmaf((float)a.x, (float)b.x, fmaf((float)a.y, (float)b.y, c));
#endif
}
__device__ __forceinline__ half2_t bc2(unsigned int u){ return __builtin_bit_cast(half2_t, u); }
__device__ __forceinline__ half2_t pack2(float a, float b){
  half2_t r; r.x = (_Float16)a; r.y = (_Float16)b; return r;   // RTNE
}
template<int CTRL>
__device__ __forceinline__ float qperm(float x){
  return __int_as_float(__builtin_amdgcn_update_dpp(0, __float_as_int(x), CTRL, 0xF, 0xF, true));
}

// ---------------- kernel 1: 3x3 second-moment stats of x over B*T ----------------
__global__ __launch_bounds__(256) void stats_kernel(const float* __restrict__ x,
                                                    float* __restrict__ stats){
  int t = blockIdx.x * 256 + threadIdx.x;
  const float4* xv = (const float4*)x + (size_t)t * 3;
  float4 a = xv[0], b = xv[1], c = xv[2];
  float x0[4] = {a.x, a.w, b.z, c.y};
  float x1[4] = {a.y, b.x, b.w, c.z};
  float x2[4] = {a.z, b.y, c.x, c.w};
  float s[9] = {0,0,0,0,0,0,0,0,0};
  #pragma unroll
  for (int r=0;r<4;++r){
    s[0]+=x0[r]; s[1]+=x1[r]; s[2]+=x2[r];
    s[3]+=x0[r]*x0[r]; s[4]+=x0[r]*x1[r]; s[5]+=x0[r]*x2[r];
    s[6]+=x1[r]*x1[r]; s[7]+=x1[r]*x2[r]; s[8]+=x2[r]*x2[r];
  }
  __shared__ float red[9][256];
  #pragma unroll
  for (int j=0;j<9;++j) red[j][threadIdx.x] = s[j];
  __syncthreads();
  if (threadIdx.x < 9){
    float sum = 0.f;
    for (int i=0;i<256;++i) sum += red[threadIdx.x][i];
    atomicAdd(&stats[threadIdx.x], sum);
  }
}

// Fold conv + BN(train stats) + gamma/beta into per-channel affine. conv_b cancels.
__device__ __forceinline__ void chan_affine(int c, const float* __restrict__ conv_w,
    const float* __restrict__ bn_g, const float* __restrict__ bn_b,
    const float* __restrict__ stats,
    float& A0, float& A1, float& A2, float& Bc){
  const float Ninv = 1.0f / (float)(B_*T_);
  float m0=stats[0]*Ninv, m1=stats[1]*Ninv, m2=stats[2]*Ninv;
  float c00=stats[3]*Ninv-m0*m0, c01=stats[4]*Ninv-m0*m1, c02=stats[5]*Ninv-m0*m2;
  float c11=stats[6]*Ninv-m1*m1, c12=stats[7]*Ninv-m1*m2, c22=stats[8]*Ninv-m2*m2;
  float w0=conv_w[c*3+0], w1=conv_w[c*3+1], w2=conv_w[c*3+2];
  float var = w0*(w0*c00 + 2.f*(w1*c01 + w2*c02)) + w1*(w1*c11 + 2.f*w2*c12) + w2*w2*c22;
  float sc = bn_g[c] * rsqrtf(var + 1e-5f);
  A0 = w0*sc; A1 = w1*sc; A2 = w2*sc;
  Bc = bn_b[c] - (w0*m0 + w1*m1 + w2*m2)*sc;
}

// ---------------- fused persistent LSTM ----------------
// 64 blocks x 512 threads (8 waves, 2/SIMD — measured optimum). thread t: k=t>>2, w=t&3.
// Per 16-step chunk: one MFMA phase computes P[s][n] = sg*(W_ih.y + b_ih + b_hh) for the
// whole chunk into LDS (thread-indexed: col=(n&127)*4+gate, row stride 514 dw -> per-step
// read is ds_read_b32 conflict-free, GEMM writes ~4-way on a 16-write once-per-chunk path).
// MFMA layouts: A row=lane&15 (timestep), k=(lane>>4)*8+j; B n=lane&15, k=(lane>>4)*8+j;
// D col=lane&15, row=(lane>>4)*4+reg (m89-verified). Gate exp2 prescale + biases folded
// into the P tile; per-step v = accv + pv. pv prefetched one step ahead (chunk-boundary
// WAR safe: passing barrier(15) implies every wave's lgkmcnt(0) drained its P reads).
// h-dot accumulators split in two (dep chain 16 -> 8 fdot2).
__global__ __launch_bounds__(512,2) void lstm_fused_kernel(
    const float* __restrict__ x,
    const float* __restrict__ conv_w, const float* __restrict__ bn_g,
    const float* __restrict__ bn_b, const float* __restrict__ stats,
    const float* __restrict__ w_ih, const float* __restrict__ b_ih,
    const float* __restrict__ b_hh, const float* __restrict__ w_hh,
    const float* __restrict__ h0, const float* __restrict__ c0,
    const float* __restrict__ out_w, const float* __restrict__ out_b,
    float* __restrict__ out){
  constexpr int CH   = 16;    // steps per MFMA chunk
  constexpr int PSTR = 514;   // P_lds row stride (dwords): 514%32=2 -> kgrp rows hit distinct banks
  int b = blockIdx.x, t = threadIdx.x;
  int k = t >> 2, w = t & 3;
  int lane = t & 63, wv = t >> 6;
  int rfrag = lane & 15, kgrp = lane >> 4;

  __shared__ __align__(16) _Float16 hbuf[2][H_];
  __shared__ __align__(16) float P_lds[CH * PSTR];   // ~33 KB

  // recurrent weights prescaled by gate exp2-scale: sg = -log2e (I,F,O), +2log2e (G)
  half2_t wh[4][16];
  #pragma unroll
  for (int g=0; g<4; ++g){
    float sg = (g==2) ? TWOLOG2E_ : -LOG2E_;
    const float4* p = (const float4*)(w_hh + (size_t)(g*H_ + k)*H_ + w*32);
    #pragma unroll
    for (int i=0;i<8;++i){
      float4 v = p[i];
      wh[g][2*i]   = pack2(sg*v.x, sg*v.y);
      wh[g][2*i+1] = pack2(sg*v.z, sg*v.w);
    }
  }
  float Aa = (w==2) ?  1.f : 0.f;
  float Bb = (w==0) ? TWOLOG2E_ : ((w==2) ? -2.f : 1.f);
  bool o1 = (w & 1) != 0;
  bool o2 = (w & 2) != 0;

  float cs = TWOLOG2E_ * c0[(size_t)b*H_ + k];      // scaled cell state (lanes 0,1 authoritative)
  if (w == 0) hbuf[0][k] = (_Float16)h0[(size_t)b*H_ + k];

  // ---- affine coefs for this lane's 16 A-channels (k = kgrp*8+j and 32+kgrp*8+j) ----
  float4 cf[16];
  #pragma unroll
  for (int j=0;j<8;++j){
    float A0,A1,A2,Bc;
    chan_affine(kgrp*8+j, conv_w, bn_g, bn_b, stats, A0,A1,A2,Bc);
    cf[j] = make_float4(A0,A1,A2,Bc);
    chan_affine(32+kgrp*8+j, conv_w, bn_g, bn_b, stats, A0,A1,A2,Bc);
    cf[8+j] = make_float4(A0,A1,A2,Bc);
  }
  // ---- B fragments + folded bias: wave wv owns cols n = g*128 + wv*16 + rfrag ----
  half8_t bf[4][2];
  float sgb[4];
  #pragma unroll
  for (int g=0; g<4; ++g){
    int n = g*H_ + wv*16 + rfrag;
    float sg = (g==2) ? TWOLOG2E_ : -LOG2E_;
    sgb[g] = sg * (b_ih[n] + b_hh[n]);
    #pragma unroll
    for (int kh=0; kh<2; ++kh){
      const float4* wp = (const float4*)(w_ih + (size_t)n*C1_ + kh*32 + kgrp*8);
      float4 u0 = wp[0], u1 = wp[1];
      half8_t hv;
      hv[0]=(_Float16)(sg*u0.x); hv[1]=(_Float16)(sg*u0.y);
      hv[2]=(_Float16)(sg*u0.z); hv[3]=(_Float16)(sg*u0.w);
      hv[4]=(_Float16)(sg*u1.x); hv[5]=(_Float16)(sg*u1.y);
      hv[6]=(_Float16)(sg*u1.z); hv[7]=(_Float16)(sg*u1.w);
      bf[g][kh] = hv;
    }
  }
  // ---- x prefetch for chunk 0 (lane's A-row = rfrag) ----
  const float* xb = x + (size_t)b*T_*3;
  float xp0, xp1, xp2;
  { const float* p = xb + 3*rfrag; xp0 = p[0]; xp1 = p[1]; xp2 = p[2]; }
  float* prd = P_lds + t;                            // per-step read base
  __syncthreads();

  for (int c = 0; c < T_/CH; ++c){
    // ===== MFMA phase: P tile for steps [c*16, c*16+16) =====
    half8_t a0, a1;
    #pragma unroll
    for (int j=0;j<8;++j){
      float4 q = cf[j];
      a0[j] = (_Float16)fmaxf(fmaf(q.x,xp0, fmaf(q.y,xp1, fmaf(q.z,xp2, q.w))), 0.f);
      float4 r = cf[8+j];
      a1[j] = (_Float16)fmaxf(fmaf(r.x,xp0, fmaf(r.y,xp1, fmaf(r.z,xp2, r.w))), 0.f);
    }
    // prefetch x for chunk c+1 (clamped; last prefetch unused)
    { int row = (c+1)*CH + rfrag; row = (row < T_) ? row : (T_-1);
      const float* p = xb + 3*row; xp0 = p[0]; xp1 = p[1]; xp2 = p[2]; }
    #pragma unroll
    for (int g=0; g<4; ++g){
      f32x4_t d = {0.f,0.f,0.f,0.f};
      d = __builtin_amdgcn_mfma_f32_16x16x32_f16(a0, bf[g][0], d, 0, 0, 0);
      d = __builtin_amdgcn_mfma_f32_16x16x32_f16(a1, bf[g][1], d, 0, 0, 0);
      int col = (wv*16 + rfrag)*4 + g;               // thread-indexed storage
      #pragma unroll
      for (int v4=0; v4<4; ++v4)
        P_lds[(kgrp*4 + v4)*PSTR + col] = d[v4] + sgb[g];
    }
    asm volatile("s_waitcnt lgkmcnt(0)" ::: "memory");
    __builtin_amdgcn_s_barrier();                    // serves as step-0 barrier too
    asm volatile("" ::: "memory");

    // ===== 16 recurrence steps =====
    float pvc = prd[0];                              // pv for step 0
    #pragma unroll
    for (int s=0; s<CH; ++s){
      int p = s & 1;                                 // c*16 even -> global parity == s&1
      if (s > 0){
        asm volatile("s_waitcnt lgkmcnt(0)" ::: "memory");
        __builtin_amdgcn_s_barrier();
        asm volatile("" ::: "memory");
      }
      const _Float16* hb = &hbuf[p][w*32];
      uint4 hv0 = *(const uint4*)(hb);
      uint4 hv1 = *(const uint4*)(hb + 8);
      uint4 hv2 = *(const uint4*)(hb + 16);
      uint4 hv3 = *(const uint4*)(hb + 24);
      float pvn = 0.f;
      if (s < CH-1) pvn = prd[(s+1)*PSTR];           // prefetch next pv (latency hidden)
      float a[4]  = {0.f,0.f,0.f,0.f};
      float a2[4] = {0.f,0.f,0.f,0.f};
      {
        half2_t h0_ = bc2(hv0.x), h1_ = bc2(hv0.y), h2_ = bc2(hv0.z), h3_ = bc2(hv0.w);
        #pragma unroll
        for (int g=0; g<4; ++g){
          a[g] = fdot2(wh[g][0], h0_, a[g]);
          a[g] = fdot2(wh[g][1], h1_, a[g]);
          a[g] = fdot2(wh[g][2], h2_, a[g]);
          a[g] = fdot2(wh[g][3], h3_, a[g]);
        }
      }
      {
        half2_t h0_ = bc2(hv1.x), h1_ = bc2(hv1.y), h2_ = bc2(hv1.z), h3_ = bc2(hv1.w);
        #pragma unroll
        for (int g=0; g<4; ++g){
          a[g] = fdot2(wh[g][4], h0_, a[g]);
          a[g] = fdot2(wh[g][5], h1_, a[g]);
          a[g] = fdot2(wh[g][6], h2_, a[g]);
          a[g] = fdot2(wh[g][7], h3_, a[g]);
        }
      }
      {
        half2_t h0_ = bc2(hv2.x), h1_ = bc2(hv2.y), h2_ = bc2(hv2.z), h3_ = bc2(hv2.w);
        #pragma unroll
        for (int g=0; g<4; ++g){
          a2[g] = fdot2(wh[g][8],  h0_, a2[g]);
          a2[g] = fdot2(wh[g][9],  h1_, a2[g]);
          a2[g] = fdot2(wh[g][10], h2_, a2[g]);
          a2[g] = fdot2(wh[g][11], h3_, a2[g]);
        }
      }
      {
        half2_t h0_ = bc2(hv3.x), h1_ = bc2(hv3.y), h2_ = bc2(hv3.z), h3_ = bc2(hv3.w);
        #pragma unroll
        for (int g=0; g<4; ++g){
          a2[g] = fdot2(wh[g][12], h0_, a2[g]);
          a2[g] = fdot2(wh[g][13], h1_, a2[g]);
          a2[g] = fdot2(wh[g][14], h2_, a2[g]);
          a2[g] = fdot2(wh[g][15], h3_, a2[g]);
        }
      }
      float g0 = a[0]+a2[0], g1 = a[1]+a2[1], g2 = a[2]+a2[2], g3 = a[3]+a2[3];
      // reduce-scatter over quad: lane w ends with gate w's total
      float b01, b23;
      { float s0 = o1 ? g0 : g1;  float k0 = o1 ? g1 : g0;
        float s1 = o1 ? g2 : g3;  float k1 = o1 ? g3 : g2;
        b01 = k0 + qperm<0xB1>(s0);
        b23 = k1 + qperm<0xB1>(s1); }
      float accv;
      { float sB = o2 ? b01 : b23;  float kB = o2 ? b23 : b01;
        accv = kB + qperm<0x4E>(sB); }
      // activation (prescaled): act = Aa + Bb*rcp(1+exp2(v)); bias folded into pv
      float v = accv + pvc;
      float e = __builtin_amdgcn_exp2f(v);
      float act = fmaf(Bb, __builtin_amdgcn_rcpf(1.f + e), Aa);
      float dA = qperm<0x1B>(act);                   // lane0 <- O
      float bp = qperm<0x4E>(act);                   // lane0 <- G
      float pp = act * (o1 ? cs : bp);               // lane0: I_s*G ; lane1: F*cs
      float cps = pp + qperm<0xB1>(pp);              // lanes 0,1: scaled c'
      cs = cps;
      float th = fmaf(-2.f, __builtin_amdgcn_rcpf(1.f + __builtin_amdgcn_exp2f(cps)), 1.f);
      float h = th * dA;
      if (w == 0) hbuf[1-p][k] = (_Float16)h;
      pvc = pvn;
    }
  }
  __syncthreads();
  // classifier epilogue on final h (T even -> buffer 0)
  if (t < NCLS_){
    float s = out_b[t];
    #pragma unroll 8
    for (int kk=0; kk<H_; ++kk)
      s = fmaf(out_w[t*H_ + kk], (float)hbuf[0][kk], s);
    out[(size_t)b*NCLS_ + t] = s;
  }
}

extern "C" void kernel_launch(void* const* d_in, const int* in_sizes, int n_in,
                              void* d_out, int out_size, void* d_ws, size_t ws_size,
                              hipStream_t stream){
  const float* x      = (const float*)d_in[0];
  const float* conv_w = (const float*)d_in[1];
  // d_in[2] = conv_b: cancels exactly inside BN(train stats) — unused
  const float* bn_g   = (const float*)d_in[3];
  const float* bn_b   = (const float*)d_in[4];
  const float* w_ih   = (const float*)d_in[5];
  const float* b_ih   = (const float*)d_in[6];
  const float* w_hh   = (const float*)d_in[7];
  const float* b_hh   = (const float*)d_in[8];
  const float* out_w  = (const float*)d_in[9];
  const float* out_b  = (const float*)d_in[10];
  const float* h0     = (const float*)d_in[11];
  const float* c0     = (const float*)d_in[12];
  float* out   = (float*)d_out;
  float* stats = (float*)d_ws;

  hipMemsetAsync(d_ws, 0, 64, stream);
  stats_kernel<<<256, 256, 0, stream>>>(x, stats);
  lstm_fused_kernel<<<B_, 512, 0, stream>>>(x, conv_w, bn_g, bn_b, stats,
                                            w_ih, b_ih, b_hh, w_hh, h0, c0,
                                            out_w, out_b, out);
}

// Round 3
// 1964.939 us; speedup vs baseline: 1.2042x; 1.1060x over previous
//
#include <hip/hip_runtime.h>
#include <cstdint>
#include <cstddef>

// Problem dims (fixed by reference)
#define B_    64
#define T_    4096
#define H_    128
#define C1_   64
#define NCLS_ 40

#define LOG2E_     1.4426950408889634f
#define TWOLOG2E_  2.8853900817779268f
#define NEG4LOG2E_ (-5.7707801635558536f)   // -2 * 2log2e

typedef _Float16 half2_t __attribute__((ext_vector_type(2)));
typedef _Float16 half8_t __attribute__((ext_vector_type(8)));
typedef float    f32x4_t __attribute__((ext_vector_type(4)));

__device__ __forceinline__ half2_t pack2(float a, float b){
  half2_t r; r.x = (_Float16)a; r.y = (_Float16)b; return r;   // RTNE
}

// ---------------- kernel 1: 3x3 second-moment stats of x over B*T ----------------
__global__ __launch_bounds__(256) void stats_kernel(const float* __restrict__ x,
                                                    float* __restrict__ stats){
  int t = blockIdx.x * 256 + threadIdx.x;
  const float4* xv = (const float4*)x + (size_t)t * 3;
  float4 a = xv[0], b = xv[1], c = xv[2];
  float x0[4] = {a.x, a.w, b.z, c.y};
  float x1[4] = {a.y, b.x, b.w, c.z};
  float x2[4] = {a.z, b.y, c.x, c.w};
  float s[9] = {0,0,0,0,0,0,0,0,0};
  #pragma unroll
  for (int r=0;r<4;++r){
    s[0]+=x0[r]; s[1]+=x1[r]; s[2]+=x2[r];
    s[3]+=x0[r]*x0[r]; s[4]+=x0[r]*x1[r]; s[5]+=x0[r]*x2[r];
    s[6]+=x1[r]*x1[r]; s[7]+=x1[r]*x2[r]; s[8]+=x2[r]*x2[r];
  }
  __shared__ float red[9][256];
  #pragma unroll
  for (int j=0;j<9;++j) red[j][threadIdx.x] = s[j];
  __syncthreads();
  if (threadIdx.x < 9){
    float sum = 0.f;
    for (int i=0;i<256;++i) sum += red[threadIdx.x][i];
    atomicAdd(&stats[threadIdx.x], sum);
  }
}

// Fold conv + BN(train stats) + gamma/beta into per-channel affine. conv_b cancels.
__device__ __forceinline__ void chan_affine(int c, const float* __restrict__ conv_w,
    const float* __restrict__ bn_g, const float* __restrict__ bn_b,
    const float* __restrict__ stats,
    float& A0, float& A1, float& A2, float& Bc){
  const float Ninv = 1.0f / (float)(B_*T_);
  float m0=stats[0]*Ninv, m1=stats[1]*Ninv, m2=stats[2]*Ninv;
  float c00=stats[3]*Ninv-m0*m0, c01=stats[4]*Ninv-m0*m1, c02=stats[5]*Ninv-m0*m2;
  float c11=stats[6]*Ninv-m1*m1, c12=stats[7]*Ninv-m1*m2, c22=stats[8]*Ninv-m2*m2;
  float w0=conv_w[c*3+0], w1=conv_w[c*3+1], w2=conv_w[c*3+2];
  float var = w0*(w0*c00 + 2.f*(w1*c01 + w2*c02)) + w1*(w1*c11 + 2.f*w2*c12) + w2*w2*c22;
  float sc = bn_g[c] * rsqrtf(var + 1e-5f);
  A0 = w0*sc; A1 = w1*sc; A2 = w2*sc;
  Bc = bn_b[c] - (w0*m0 + w1*m1 + w2*m2)*sc;
}

// ---------------- fused persistent LSTM, MFMA recurrence ----------------
// 64 blocks x 512 threads (8 waves, 2/SIMD). Per 16-step chunk, a blob phase MFMAs
// P[s][n] = sg*(W_ih.relu(affine(x)) + b_ih + b_hh) into LDS (layout: row s, dword
// col (n&127)*4 + gate, row stride 516 dw -> per-step P read is ONE aligned
// ds_read_b128 giving the lane its element's 4 gates).
// Recurrence per step on the MATRIX pipe: D = W_hh-tile x h-broadcast.
//   wave wv owns elements k in [wv*16, wv*16+16), all 4 gates (4 tiles x 4 K-chunks,
//   16 mfma_f32_16x16x32_f16, weights stationary in 64 VGPR, sg prescale folded).
//   B-frag: h[kc*32 + kgrp*8 + j] (col-independent -> D columns replicated).
//   D: col=lane&15, row=(lane>>4)*4+v (verified layout). Lane picks element
//   e=(lane&15)>>2 via cndmask -> holds I,F,G,O in-lane: no quad reduce, no dpp
//   chain; tail fully scalar, 4-way redundant over r=(lane&15)&3, writer r==0.
// cs carried scaled by 2log2e. One barrier per step (RAW h exchange), lgkmcnt-only
// drain. pv prefetched one step ahead; chunk-boundary WAR safe (all P reads for the
// chunk complete before the step-15 barrier).
__global__ __launch_bounds__(512,2) void lstm_fused_kernel(
    const float* __restrict__ x,
    const float* __restrict__ conv_w, const float* __restrict__ bn_g,
    const float* __restrict__ bn_b, const float* __restrict__ stats,
    const float* __restrict__ w_ih, const float* __restrict__ b_ih,
    const float* __restrict__ b_hh, const float* __restrict__ w_hh,
    const float* __restrict__ h0, const float* __restrict__ c0,
    const float* __restrict__ out_w, const float* __restrict__ out_b,
    float* __restrict__ out){
  constexpr int CH   = 16;    // steps per chunk
  constexpr int PSTR = 516;   // P row stride in dwords: 516*4 = 2064 B, 16B aligned
  int b = blockIdx.x, t = threadIdx.x;
  int lane = t & 63, wv = t >> 6;
  int rfrag = lane & 15, kgrp = lane >> 4;
  int e  = rfrag >> 2, r3 = rfrag & 3;
  int kstar = wv*16 + kgrp*4 + e;                 // this lane's h element
  bool eb1 = (e & 1) != 0, eb2 = (e & 2) != 0;

  __shared__ __align__(16) _Float16 hbuf[2][H_];
  __shared__ __align__(16) float P_lds[CH * PSTR];
  __shared__ __align__(16) float4 cf_lds[C1_];

  if (t < C1_){
    float A0,A1,A2,Bc; chan_affine(t, conv_w, bn_g, bn_b, stats, A0,A1,A2,Bc);
    cf_lds[t] = make_float4(A0,A1,A2,Bc);
  }

  // ---- stationary recurrent-weight A-frags: Af[g][kc], sg prescale folded ----
  half8_t Af[4][4];
  #pragma unroll
  for (int g=0; g<4; ++g){
    float sg = (g==2) ? TWOLOG2E_ : -LOG2E_;
    #pragma unroll
    for (int kc=0; kc<4; ++kc){
      const float4* wp = (const float4*)(w_hh + (size_t)(g*H_ + wv*16 + rfrag)*H_ + kc*32 + kgrp*8);
      float4 u0 = wp[0], u1 = wp[1];
      half8_t hv;
      hv[0]=(_Float16)(sg*u0.x); hv[1]=(_Float16)(sg*u0.y);
      hv[2]=(_Float16)(sg*u0.z); hv[3]=(_Float16)(sg*u0.w);
      hv[4]=(_Float16)(sg*u1.x); hv[5]=(_Float16)(sg*u1.y);
      hv[6]=(_Float16)(sg*u1.z); hv[7]=(_Float16)(sg*u1.w);
      Af[g][kc] = hv;
    }
  }
  // ---- producer B-frags (W_ih) + folded biases: wave wv owns n = g*128+wv*16+rfrag ----
  half8_t bf[4][2];
  float sgb[4];
  #pragma unroll
  for (int g=0; g<4; ++g){
    int n = g*H_ + wv*16 + rfrag;
    float sg = (g==2) ? TWOLOG2E_ : -LOG2E_;
    sgb[g] = sg * (b_ih[n] + b_hh[n]);
    #pragma unroll
    for (int kh=0; kh<2; ++kh){
      const float4* wp = (const float4*)(w_ih + (size_t)n*C1_ + kh*32 + kgrp*8);
      float4 u0 = wp[0], u1 = wp[1];
      half8_t hv;
      hv[0]=(_Float16)(sg*u0.x); hv[1]=(_Float16)(sg*u0.y);
      hv[2]=(_Float16)(sg*u0.z); hv[3]=(_Float16)(sg*u0.w);
      hv[4]=(_Float16)(sg*u1.x); hv[5]=(_Float16)(sg*u1.y);
      hv[6]=(_Float16)(sg*u1.z); hv[7]=(_Float16)(sg*u1.w);
      bf[g][kh] = hv;
    }
  }

  float cs = TWOLOG2E_ * c0[(size_t)b*H_ + kstar];   // scaled cell state (4x lane-redundant)
  if (r3 == 0) hbuf[0][kstar] = (_Float16)h0[(size_t)b*H_ + kstar];

  // ---- x prefetch for chunk 0 (producer A-row = timestep rfrag) ----
  const float* xb = x + (size_t)b*T_*3;
  float xp0, xp1, xp2;
  { const float* p = xb + 3*rfrag; xp0 = p[0]; xp1 = p[1]; xp2 = p[2]; }
  __syncthreads();

  for (int c = 0; c < T_/CH; ++c){
    // ===== blob: P tile for steps [c*16, c*16+16) =====
    half8_t a0, a1;
    #pragma unroll
    for (int j=0;j<8;++j){
      float4 q = cf_lds[kgrp*8+j];
      a0[j] = (_Float16)fmaxf(fmaf(q.x,xp0, fmaf(q.y,xp1, fmaf(q.z,xp2, q.w))), 0.f);
      float4 rr = cf_lds[32+kgrp*8+j];
      a1[j] = (_Float16)fmaxf(fmaf(rr.x,xp0, fmaf(rr.y,xp1, fmaf(rr.z,xp2, rr.w))), 0.f);
    }
    { int row = (c+1)*CH + rfrag; row = (row < T_) ? row : (T_-1);
      const float* p = xb + 3*row; xp0 = p[0]; xp1 = p[1]; xp2 = p[2]; }
    #pragma unroll
    for (int g=0; g<4; ++g){
      f32x4_t dp = {0.f,0.f,0.f,0.f};
      dp = __builtin_amdgcn_mfma_f32_16x16x32_f16(a0, bf[g][0], dp, 0, 0, 0);
      dp = __builtin_amdgcn_mfma_f32_16x16x32_f16(a1, bf[g][1], dp, 0, 0, 0);
      int col = (wv*16 + rfrag)*4 + g;             // element-major, gate-minor
      #pragma unroll
      for (int v4=0; v4<4; ++v4)
        P_lds[(kgrp*4 + v4)*PSTR + col] = dp[v4] + sgb[g];
    }
    asm volatile("s_waitcnt lgkmcnt(0)" ::: "memory");
    __builtin_amdgcn_s_barrier();                  // serves as step-0 barrier too
    asm volatile("" ::: "memory");

    // pv for step 0: lane's 4 gates, one b128
    f32x4_t pq = *(const f32x4_t*)(P_lds + (size_t)kstar*4);

    // ===== 16 recurrence steps =====
    #pragma unroll
    for (int s=0; s<CH; ++s){
      int p = s & 1;                               // c*16 even -> parity == s&1
      if (s > 0){
        asm volatile("s_waitcnt lgkmcnt(0)" ::: "memory");
        __builtin_amdgcn_s_barrier();
        asm volatile("" ::: "memory");
      }
      const _Float16* hb = hbuf[p];
      uint4 hu0 = *(const uint4*)(hb + 0*32 + kgrp*8);
      uint4 hu1 = *(const uint4*)(hb + 1*32 + kgrp*8);
      uint4 hu2 = *(const uint4*)(hb + 2*32 + kgrp*8);
      uint4 hu3 = *(const uint4*)(hb + 3*32 + kgrp*8);
      f32x4_t pqn = pq;
      if (s < CH-1) pqn = *(const f32x4_t*)(P_lds + (size_t)(s+1)*PSTR + kstar*4);
      half8_t B0 = __builtin_bit_cast(half8_t, hu0);
      half8_t B1 = __builtin_bit_cast(half8_t, hu1);
      half8_t B2 = __builtin_bit_cast(half8_t, hu2);
      half8_t B3 = __builtin_bit_cast(half8_t, hu3);
      f32x4_t d0 = {0.f,0.f,0.f,0.f}, d1 = {0.f,0.f,0.f,0.f};
      f32x4_t d2 = {0.f,0.f,0.f,0.f}, d3 = {0.f,0.f,0.f,0.f};
      // 4 independent 4-deep chains; matrix pipe, VALU stays free
      d0 = __builtin_amdgcn_mfma_f32_16x16x32_f16(Af[0][0], B0, d0, 0,0,0);
      d1 = __builtin_amdgcn_mfma_f32_16x16x32_f16(Af[1][0], B0, d1, 0,0,0);
      d2 = __builtin_amdgcn_mfma_f32_16x16x32_f16(Af[2][0], B0, d2, 0,0,0);
      d3 = __builtin_amdgcn_mfma_f32_16x16x32_f16(Af[3][0], B0, d3, 0,0,0);
      d0 = __builtin_amdgcn_mfma_f32_16x16x32_f16(Af[0][1], B1, d0, 0,0,0);
      d1 = __builtin_amdgcn_mfma_f32_16x16x32_f16(Af[1][1], B1, d1, 0,0,0);
      d2 = __builtin_amdgcn_mfma_f32_16x16x32_f16(Af[2][1], B1, d2, 0,0,0);
      d3 = __builtin_amdgcn_mfma_f32_16x16x32_f16(Af[3][1], B1, d3, 0,0,0);
      d0 = __builtin_amdgcn_mfma_f32_16x16x32_f16(Af[0][2], B2, d0, 0,0,0);
      d1 = __builtin_amdgcn_mfma_f32_16x16x32_f16(Af[1][2], B2, d1, 0,0,0);
      d2 = __builtin_amdgcn_mfma_f32_16x16x32_f16(Af[2][2], B2, d2, 0,0,0);
      d3 = __builtin_amdgcn_mfma_f32_16x16x32_f16(Af[3][2], B2, d3, 0,0,0);
      d0 = __builtin_amdgcn_mfma_f32_16x16x32_f16(Af[0][3], B3, d0, 0,0,0);
      d1 = __builtin_amdgcn_mfma_f32_16x16x32_f16(Af[1][3], B3, d1, 0,0,0);
      d2 = __builtin_amdgcn_mfma_f32_16x16x32_f16(Af[2][3], B3, d2, 0,0,0);
      d3 = __builtin_amdgcn_mfma_f32_16x16x32_f16(Af[3][3], B3, d3, 0,0,0);
      // pick component e (the lane's element) from each gate tile
      float sI, sF, sG, sO;
      { float v01 = eb1 ? d0[1] : d0[0]; float v23 = eb1 ? d0[3] : d0[2]; sI = eb2 ? v23 : v01; }
      { float v01 = eb1 ? d1[1] : d1[0]; float v23 = eb1 ? d1[3] : d1[2]; sF = eb2 ? v23 : v01; }
      { float v01 = eb1 ? d2[1] : d2[0]; float v23 = eb1 ? d2[3] : d2[2]; sG = eb2 ? v23 : v01; }
      { float v01 = eb1 ? d3[1] : d3[0]; float v23 = eb1 ? d3[3] : d3[2]; sO = eb2 ? v23 : v01; }
      // prescaled pre-activations (sg folded into W and P)
      float vI = sI + pq[0], vF = sF + pq[1], vG = sG + pq[2], vO = sO + pq[3];
      float rI = __builtin_amdgcn_rcpf(1.f + __builtin_amdgcn_exp2f(vI));  // sigmoid(i)
      float rF = __builtin_amdgcn_rcpf(1.f + __builtin_amdgcn_exp2f(vF));  // sigmoid(f)
      float rG = __builtin_amdgcn_rcpf(1.f + __builtin_amdgcn_exp2f(vG));  // -> tanh(g)
      float rO = __builtin_amdgcn_rcpf(1.f + __builtin_amdgcn_exp2f(vO));  // sigmoid(o)
      float gT2 = fmaf(NEG4LOG2E_, rG, TWOLOG2E_);   // 2log2e * tanh(g)
      float cn  = fmaf(rF, cs, rI * gT2);            // scaled c'
      cs = cn;
      float th = fmaf(-2.f, __builtin_amdgcn_rcpf(1.f + __builtin_amdgcn_exp2f(cn)), 1.f);
      float h  = rO * th;
      if (r3 == 0) hbuf[1-p][kstar] = (_Float16)h;
      pq = pqn;
    }
  }
  __syncthreads();
  // classifier epilogue on final h (T even -> buffer 0)
  if (t < NCLS_){
    float s = out_b[t];
    #pragma unroll 8
    for (int kk=0; kk<H_; ++kk)
      s = fmaf(out_w[t*H_ + kk], (float)hbuf[0][kk], s);
    out[(size_t)b*NCLS_ + t] = s;
  }
}

extern "C" void kernel_launch(void* const* d_in, const int* in_sizes, int n_in,
                              void* d_out, int out_size, void* d_ws, size_t ws_size,
                              hipStream_t stream){
  const float* x      = (const float*)d_in[0];
  const float* conv_w = (const float*)d_in[1];
  // d_in[2] = conv_b: cancels exactly inside BN(train stats) — unused
  const float* bn_g   = (const float*)d_in[3];
  const float* bn_b   = (const float*)d_in[4];
  const float* w_ih   = (const float*)d_in[5];
  const float* b_ih   = (const float*)d_in[6];
  const float* w_hh   = (const float*)d_in[7];
  const float* b_hh   = (const float*)d_in[8];
  const float* out_w  = (const float*)d_in[9];
  const float* out_b  = (const float*)d_in[10];
  const float* h0     = (const float*)d_in[11];
  const float* c0     = (const float*)d_in[12];
  float* out   = (float*)d_out;
  float* stats = (float*)d_ws;

  hipMemsetAsync(d_ws, 0, 64, stream);
  stats_kernel<<<256, 256, 0, stream>>>(x, stats);
  lstm_fused_kernel<<<B_, 512, 0, stream>>>(x, conv_w, bn_g, bn_b, stats,
                                            w_ih, b_ih, b_hh, w_hh, h0, c0,
                                            out_w, out_b, out);
}

// Round 4
// 1683.646 us; speedup vs baseline: 1.4054x; 1.1671x over previous
//
#include <hip/hip_runtime.h>
#include <cstdint>
#include <cstddef>

// Problem dims (fixed by reference)
#define B_    64
#define T_    4096
#define H_    128
#define C1_   64
#define NCLS_ 40

#define LOG2E_     1.4426950408889634f
#define TWOLOG2E_  2.8853900817779268f
#define NEG4LOG2E_ (-5.7707801635558536f)   // -2 * 2log2e

typedef _Float16 half2_t __attribute__((ext_vector_type(2)));
typedef _Float16 half8_t __attribute__((ext_vector_type(8)));
typedef float    f32x4_t __attribute__((ext_vector_type(4)));

__device__ __forceinline__ half2_t pack2(float a, float b){
  half2_t r; r.x = (_Float16)a; r.y = (_Float16)b; return r;   // RTNE
}

// ---------------- kernel 1: 3x3 second-moment stats of x over B*T ----------------
__global__ __launch_bounds__(256) void stats_kernel(const float* __restrict__ x,
                                                    float* __restrict__ stats){
  int t = blockIdx.x * 256 + threadIdx.x;
  const float4* xv = (const float4*)x + (size_t)t * 3;
  float4 a = xv[0], b = xv[1], c = xv[2];
  float x0[4] = {a.x, a.w, b.z, c.y};
  float x1[4] = {a.y, b.x, b.w, c.z};
  float x2[4] = {a.z, b.y, c.x, c.w};
  float s[9] = {0,0,0,0,0,0,0,0,0};
  #pragma unroll
  for (int r=0;r<4;++r){
    s[0]+=x0[r]; s[1]+=x1[r]; s[2]+=x2[r];
    s[3]+=x0[r]*x0[r]; s[4]+=x0[r]*x1[r]; s[5]+=x0[r]*x2[r];
    s[6]+=x1[r]*x1[r]; s[7]+=x1[r]*x2[r]; s[8]+=x2[r]*x2[r];
  }
  __shared__ float red[9][256];
  #pragma unroll
  for (int j=0;j<9;++j) red[j][threadIdx.x] = s[j];
  __syncthreads();
  if (threadIdx.x < 9){
    float sum = 0.f;
    for (int i=0;i<256;++i) sum += red[threadIdx.x][i];
    atomicAdd(&stats[threadIdx.x], sum);
  }
}

// Fold conv + BN(train stats) + gamma/beta into per-channel affine. conv_b cancels.
__device__ __forceinline__ void chan_affine(int c, const float* __restrict__ conv_w,
    const float* __restrict__ bn_g, const float* __restrict__ bn_b,
    const float* __restrict__ stats,
    float& A0, float& A1, float& A2, float& Bc){
  const float Ninv = 1.0f / (float)(B_*T_);
  float m0=stats[0]*Ninv, m1=stats[1]*Ninv, m2=stats[2]*Ninv;
  float c00=stats[3]*Ninv-m0*m0, c01=stats[4]*Ninv-m0*m1, c02=stats[5]*Ninv-m0*m2;
  float c11=stats[6]*Ninv-m1*m1, c12=stats[7]*Ninv-m1*m2, c22=stats[8]*Ninv-m2*m2;
  float w0=conv_w[c*3+0], w1=conv_w[c*3+1], w2=conv_w[c*3+2];
  float var = w0*(w0*c00 + 2.f*(w1*c01 + w2*c02)) + w1*(w1*c11 + 2.f*w2*c12) + w2*w2*c22;
  float sc = bn_g[c] * rsqrtf(var + 1e-5f);
  A0 = w0*sc; A1 = w1*sc; A2 = w2*sc;
  Bc = bn_b[c] - (w0*m0 + w1*m1 + w2*m2)*sc;
}

// ---------------- fused persistent LSTM, transposed-MFMA recurrence ----------------
// 64 blocks x 512 threads (8 waves, 2/SIMD). Per 16-step chunk, a blob phase MFMAs
// P[s][n] = sg*(W_ih.relu(affine(x)) + b_ih + b_hh) into LDS (row s, dword col
// (n&127)*4 + gate, row stride 516 dw).
// Recurrence per step on the MATRIX pipe, TRANSPOSED: D = A(h-bcast) x B(W_hh^T).
//   A-frag: A[r][k] = h[kc*32 + kgrp*8 + j] — row-independent -> all D rows equal.
//   B-frag: B[k][n] = sg*w_hh[g*128 + wv*16 + rfrag][kc*32 + kgrp*8 + j]
//           (same loads as before, relabeled; stationary in 64 VGPR).
//   D[r][c] = gate-g preact of element wv*16+c, replicated over r -> lane reads
//   d[0] directly: NO component picks, NO reduce. Lane owns element wv*16+rfrag
//   with all 4 gates in-lane (4-way kgrp redundancy; kgrp==0 lanes write h).
//   C-init: hoisted zero vector Z -> no per-step init movs; pq added after.
// cs carried scaled by 2log2e. One barrier per step (lgkmcnt-only drain). pq
// prefetched one step ahead; chunk-boundary WAR safe (same proof as prior round).
__global__ __launch_bounds__(512,2) void lstm_fused_kernel(
    const float* __restrict__ x,
    const float* __restrict__ conv_w, const float* __restrict__ bn_g,
    const float* __restrict__ bn_b, const float* __restrict__ stats,
    const float* __restrict__ w_ih, const float* __restrict__ b_ih,
    const float* __restrict__ b_hh, const float* __restrict__ w_hh,
    const float* __restrict__ h0, const float* __restrict__ c0,
    const float* __restrict__ out_w, const float* __restrict__ out_b,
    float* __restrict__ out){
  constexpr int CH   = 16;    // steps per chunk
  constexpr int PSTR = 516;   // P row stride in dwords: 516*4 = 2064 B, 16B aligned
  int b = blockIdx.x, t = threadIdx.x;
  int lane = t & 63, wv = t >> 6;
  int rfrag = lane & 15, kgrp = lane >> 4;
  int estar = wv*16 + rfrag;                      // this lane's h element
  bool wrt = (kgrp == 0);

  __shared__ __align__(16) _Float16 hbuf[2][H_];
  __shared__ __align__(16) float P_lds[CH * PSTR];
  __shared__ __align__(16) float4 cf_lds[C1_];

  if (t < C1_){
    float A0,A1,A2,Bc; chan_affine(t, conv_w, bn_g, bn_b, stats, A0,A1,A2,Bc);
    cf_lds[t] = make_float4(A0,A1,A2,Bc);
  }

  // ---- stationary recurrent weights as B-frags: Wf[g][kc], sg prescale folded ----
  // lane supplies B[k][n]: n = rfrag (gate-row g*128 + wv*16 + rfrag), k = kc*32+kgrp*8+j
  half8_t Wf[4][4];
  #pragma unroll
  for (int g=0; g<4; ++g){
    float sg = (g==2) ? TWOLOG2E_ : -LOG2E_;
    #pragma unroll
    for (int kc=0; kc<4; ++kc){
      const float4* wp = (const float4*)(w_hh + (size_t)(g*H_ + wv*16 + rfrag)*H_ + kc*32 + kgrp*8);
      float4 u0 = wp[0], u1 = wp[1];
      half8_t hv;
      hv[0]=(_Float16)(sg*u0.x); hv[1]=(_Float16)(sg*u0.y);
      hv[2]=(_Float16)(sg*u0.z); hv[3]=(_Float16)(sg*u0.w);
      hv[4]=(_Float16)(sg*u1.x); hv[5]=(_Float16)(sg*u1.y);
      hv[6]=(_Float16)(sg*u1.z); hv[7]=(_Float16)(sg*u1.w);
      Wf[g][kc] = hv;
    }
  }
  // ---- producer B-frags (W_ih) + folded biases: wave wv owns n = g*128+wv*16+rfrag ----
  half8_t bf[4][2];
  float sgb[4];
  #pragma unroll
  for (int g=0; g<4; ++g){
    int n = g*H_ + wv*16 + rfrag;
    float sg = (g==2) ? TWOLOG2E_ : -LOG2E_;
    sgb[g] = sg * (b_ih[n] + b_hh[n]);
    #pragma unroll
    for (int kh=0; kh<2; ++kh){
      const float4* wp = (const float4*)(w_ih + (size_t)n*C1_ + kh*32 + kgrp*8);
      float4 u0 = wp[0], u1 = wp[1];
      half8_t hv;
      hv[0]=(_Float16)(sg*u0.x); hv[1]=(_Float16)(sg*u0.y);
      hv[2]=(_Float16)(sg*u0.z); hv[3]=(_Float16)(sg*u0.w);
      hv[4]=(_Float16)(sg*u1.x); hv[5]=(_Float16)(sg*u1.y);
      hv[6]=(_Float16)(sg*u1.z); hv[7]=(_Float16)(sg*u1.w);
      bf[g][kh] = hv;
    }
  }

  float cs = TWOLOG2E_ * c0[(size_t)b*H_ + estar];   // scaled cell state (kgrp-redundant)
  if (wrt) hbuf[0][estar] = (_Float16)h0[(size_t)b*H_ + estar];

  // ---- x prefetch for chunk 0 (producer A-row = timestep rfrag) ----
  const float* xb = x + (size_t)b*T_*3;
  float xp0, xp1, xp2;
  { const float* p = xb + 3*rfrag; xp0 = p[0]; xp1 = p[1]; xp2 = p[2]; }
  const f32x4_t Z = {0.f, 0.f, 0.f, 0.f};            // hoisted MFMA C-init
  __syncthreads();

  for (int c = 0; c < T_/CH; ++c){
    // ===== blob: P tile for steps [c*16, c*16+16) =====
    half8_t a0, a1;
    #pragma unroll
    for (int j=0;j<8;++j){
      float4 q = cf_lds[kgrp*8+j];
      a0[j] = (_Float16)fmaxf(fmaf(q.x,xp0, fmaf(q.y,xp1, fmaf(q.z,xp2, q.w))), 0.f);
      float4 rr = cf_lds[32+kgrp*8+j];
      a1[j] = (_Float16)fmaxf(fmaf(rr.x,xp0, fmaf(rr.y,xp1, fmaf(rr.z,xp2, rr.w))), 0.f);
    }
    { int row = (c+1)*CH + rfrag; row = (row < T_) ? row : (T_-1);
      const float* p = xb + 3*row; xp0 = p[0]; xp1 = p[1]; xp2 = p[2]; }
    #pragma unroll
    for (int g=0; g<4; ++g){
      f32x4_t dp = __builtin_amdgcn_mfma_f32_16x16x32_f16(a0, bf[g][0], Z, 0, 0, 0);
      dp = __builtin_amdgcn_mfma_f32_16x16x32_f16(a1, bf[g][1], dp, 0, 0, 0);
      int col = (wv*16 + rfrag)*4 + g;             // element-major, gate-minor
      #pragma unroll
      for (int v4=0; v4<4; ++v4)
        P_lds[(kgrp*4 + v4)*PSTR + col] = dp[v4] + sgb[g];
    }
    asm volatile("s_waitcnt lgkmcnt(0)" ::: "memory");
    __builtin_amdgcn_s_barrier();                  // serves as step-0 barrier too
    asm volatile("" ::: "memory");

    // pv for step 0: lane's element, 4 gates, one b128
    f32x4_t pq = *(const f32x4_t*)(P_lds + (size_t)estar*4);

    // ===== 16 recurrence steps =====
    #pragma unroll
    for (int s=0; s<CH; ++s){
      int p = s & 1;                               // c*16 even -> parity == s&1
      if (s > 0){
        asm volatile("s_waitcnt lgkmcnt(0)" ::: "memory");
        __builtin_amdgcn_s_barrier();
        asm volatile("" ::: "memory");
      }
      const _Float16* hb = hbuf[p];
      // A-frags: h broadcast (16-lane same-address reads, conflict-free)
      uint4 hu0 = *(const uint4*)(hb + 0*32 + kgrp*8);
      uint4 hu1 = *(const uint4*)(hb + 1*32 + kgrp*8);
      uint4 hu2 = *(const uint4*)(hb + 2*32 + kgrp*8);
      uint4 hu3 = *(const uint4*)(hb + 3*32 + kgrp*8);
      f32x4_t pqn = pq;
      if (s < CH-1) pqn = *(const f32x4_t*)(P_lds + (size_t)(s+1)*PSTR + estar*4);
      half8_t A0 = __builtin_bit_cast(half8_t, hu0);
      half8_t A1 = __builtin_bit_cast(half8_t, hu1);
      half8_t A2 = __builtin_bit_cast(half8_t, hu2);
      half8_t A3 = __builtin_bit_cast(half8_t, hu3);
      // 4 independent 4-deep chains on the matrix pipe; C-init from hoisted Z
      f32x4_t d0 = __builtin_amdgcn_mfma_f32_16x16x32_f16(A0, Wf[0][0], Z, 0,0,0);
      f32x4_t d1 = __builtin_amdgcn_mfma_f32_16x16x32_f16(A0, Wf[1][0], Z, 0,0,0);
      f32x4_t d2 = __builtin_amdgcn_mfma_f32_16x16x32_f16(A0, Wf[2][0], Z, 0,0,0);
      f32x4_t d3 = __builtin_amdgcn_mfma_f32_16x16x32_f16(A0, Wf[3][0], Z, 0,0,0);
      d0 = __builtin_amdgcn_mfma_f32_16x16x32_f16(A1, Wf[0][1], d0, 0,0,0);
      d1 = __builtin_amdgcn_mfma_f32_16x16x32_f16(A1, Wf[1][1], d1, 0,0,0);
      d2 = __builtin_amdgcn_mfma_f32_16x16x32_f16(A1, Wf[2][1], d2, 0,0,0);
      d3 = __builtin_amdgcn_mfma_f32_16x16x32_f16(A1, Wf[3][1], d3, 0,0,0);
      d0 = __builtin_amdgcn_mfma_f32_16x16x32_f16(A2, Wf[0][2], d0, 0,0,0);
      d1 = __builtin_amdgcn_mfma_f32_16x16x32_f16(A2, Wf[1][2], d1, 0,0,0);
      d2 = __builtin_amdgcn_mfma_f32_16x16x32_f16(A2, Wf[2][2], d2, 0,0,0);
      d3 = __builtin_amdgcn_mfma_f32_16x16x32_f16(A2, Wf[3][2], d3, 0,0,0);
      d0 = __builtin_amdgcn_mfma_f32_16x16x32_f16(A3, Wf[0][3], d0, 0,0,0);
      d1 = __builtin_amdgcn_mfma_f32_16x16x32_f16(A3, Wf[1][3], d1, 0,0,0);
      d2 = __builtin_amdgcn_mfma_f32_16x16x32_f16(A3, Wf[2][3], d2, 0,0,0);
      d3 = __builtin_amdgcn_mfma_f32_16x16x32_f16(A3, Wf[3][3], d3, 0,0,0);
      // component 0 == lane's element (all components replicated) — no picks
      float vI = d0[0] + pq[0];
      float vF = d1[0] + pq[1];
      float vG = d2[0] + pq[2];
      float vO = d3[0] + pq[3];
      float rI = __builtin_amdgcn_rcpf(1.f + __builtin_amdgcn_exp2f(vI));  // sigmoid(i)
      float rF = __builtin_amdgcn_rcpf(1.f + __builtin_amdgcn_exp2f(vF));  // sigmoid(f)
      float rG = __builtin_amdgcn_rcpf(1.f + __builtin_amdgcn_exp2f(vG));  // -> tanh(g)
      float rO = __builtin_amdgcn_rcpf(1.f + __builtin_amdgcn_exp2f(vO));  // sigmoid(o)
      float gT2 = fmaf(NEG4LOG2E_, rG, TWOLOG2E_);   // 2log2e * tanh(g)
      float cn  = fmaf(rF, cs, rI * gT2);            // scaled c'
      cs = cn;
      float th = fmaf(-2.f, __builtin_amdgcn_rcpf(1.f + __builtin_amdgcn_exp2f(cn)), 1.f);
      float h  = rO * th;
      if (wrt) hbuf[1-p][estar] = (_Float16)h;
      pq = pqn;
    }
  }
  __syncthreads();
  // classifier epilogue on final h (T even -> buffer 0)
  if (t < NCLS_){
    float s = out_b[t];
    #pragma unroll 8
    for (int kk=0; kk<H_; ++kk)
      s = fmaf(out_w[t*H_ + kk], (float)hbuf[0][kk], s);
    out[(size_t)b*NCLS_ + t] = s;
  }
}

extern "C" void kernel_launch(void* const* d_in, const int* in_sizes, int n_in,
                              void* d_out, int out_size, void* d_ws, size_t ws_size,
                              hipStream_t stream){
  const float* x      = (const float*)d_in[0];
  const float* conv_w = (const float*)d_in[1];
  // d_in[2] = conv_b: cancels exactly inside BN(train stats) — unused
  const float* bn_g   = (const float*)d_in[3];
  const float* bn_b   = (const float*)d_in[4];
  const float* w_ih   = (const float*)d_in[5];
  const float* b_ih   = (const float*)d_in[6];
  const float* w_hh   = (const float*)d_in[7];
  const float* b_hh   = (const float*)d_in[8];
  const float* out_w  = (const float*)d_in[9];
  const float* out_b  = (const float*)d_in[10];
  const float* h0     = (const float*)d_in[11];
  const float* c0     = (const float*)d_in[12];
  float* out   = (float*)d_out;
  float* stats = (float*)d_ws;

  hipMemsetAsync(d_ws, 0, 64, stream);
  stats_kernel<<<256, 256, 0, stream>>>(x, stats);
  lstm_fused_kernel<<<B_, 512, 0, stream>>>(x, conv_w, bn_g, bn_b, stats,
                                            w_ih, b_ih, b_hh, w_hh, h0, c0,
                                            out_w, out_b, out);
}